// Round 1
// baseline (777.800 us; speedup 1.0000x reference)
//
#include <hip/hip_runtime.h>
#include <hip/hip_bf16.h>

#define H 128
#define GBM 64
#define GBN 64

// ---------------- norm / CSR build ----------------

__global__ void k_init_dinv(float* __restrict__ dinv, int n) {
  int i = blockIdx.x * 256 + threadIdx.x;
  if (i < n) dinv[i] = 1.0f;  // self-loop weight
}

__global__ void k_deg_count(const int* __restrict__ col, const float* __restrict__ w,
                            float* __restrict__ deg, int* __restrict__ cnt, int E) {
  int e = blockIdx.x * 256 + threadIdx.x;
  if (e >= E) return;
  int c = col[e];
  atomicAdd(&deg[c], w[e]);
  atomicAdd(&cnt[c], 1);
}

__global__ void k_dinv(float* __restrict__ dinv, int n) {
  int i = blockIdx.x * 256 + threadIdx.x;
  if (i < n) dinv[i] = 1.0f / sqrtf(dinv[i]);  // deg >= 1 always (self loop)
}

__global__ void k_scan1(const int* __restrict__ cnt, int* __restrict__ offs,
                        int* __restrict__ bsums, int n) {
  __shared__ int s[256];
  int t = threadIdx.x, i = blockIdx.x * 256 + t;
  int v = (i < n) ? cnt[i] : 0;
  s[t] = v; __syncthreads();
  for (int off = 1; off < 256; off <<= 1) {
    int x = 0;
    if (t >= off) x = s[t - off];
    __syncthreads();
    if (t >= off) s[t] += x;
    __syncthreads();
  }
  if (i < n) offs[i] = s[t] - v;          // exclusive scan within block
  if (t == 255) bsums[blockIdx.x] = s[t]; // block total
}

__global__ void k_scan2(int* __restrict__ bsums, int nb) {
  __shared__ int s[512];
  int t = threadIdx.x;
  int v = (t < nb) ? bsums[t] : 0;
  s[t] = v; __syncthreads();
  for (int off = 1; off < 512; off <<= 1) {
    int x = 0;
    if (t >= off) x = s[t - off];
    __syncthreads();
    if (t >= off) s[t] += x;
    __syncthreads();
  }
  if (t < nb) bsums[t] = s[t] - v;        // exclusive scan of block sums
}

__global__ void k_scan3(int* __restrict__ offs, const int* __restrict__ bsums, int n) {
  int i = blockIdx.x * 256 + threadIdx.x;
  if (i < n) offs[i] += bsums[blockIdx.x];
}

__global__ void k_fill(const int* __restrict__ row, const int* __restrict__ col,
                       const float* __restrict__ ew, const float* __restrict__ dinv,
                       const int* __restrict__ offs, int* __restrict__ cur,
                       int2* __restrict__ elist, int E) {
  int e = blockIdx.x * 256 + threadIdx.x;
  if (e >= E) return;
  int c = col[e], r = row[e];
  int pos = offs[c] + atomicAdd(&cur[c], 1);
  float nrm = dinv[r] * ew[e] * dinv[c];
  elist[pos] = make_int2(r, __float_as_int(nrm));
}

// ---------------- GEMM: Y[r] = X[gidx? gidx[r] : r] @ W  (fp32, 64x64 tile) ----------------

#define FMA4(A, xs, wv) { A[0] = fmaf(xs, wv.x, A[0]); A[1] = fmaf(xs, wv.y, A[1]); \
                          A[2] = fmaf(xs, wv.z, A[2]); A[3] = fmaf(xs, wv.w, A[3]); }

__global__ __launch_bounds__(256, 2) void k_gemm(const float* __restrict__ X,
    const int* __restrict__ gidx, const float* __restrict__ Wg,
    float* __restrict__ Y, int Nrows) {
  __shared__ float Ws[H][GBN + 4];  // pad to 68 floats: 16B-aligned rows, 2-way (free) conflicts
  int tid = threadIdx.x;
  int bm = blockIdx.x * GBM;
  int bn = blockIdx.y * GBN;
  for (int i = tid; i < H * (GBN / 4); i += 256) {
    int k = i >> 4, c4 = (i & 15) * 4;
    *(float4*)&Ws[k][c4] = *(const float4*)(Wg + k * H + bn + c4);
  }
  __syncthreads();
  int rg = tid >> 4, cg = tid & 15;
  int cg4 = cg * 4;
  const float* xp0; const float* xp1; const float* xp2; const float* xp3;
  int g0 = bm + rg * 4 + 0, g1 = g0 + 1, g2 = g0 + 2, g3 = g0 + 3;
  {
    int c0 = g0 < Nrows ? g0 : Nrows - 1;
    int c1 = g1 < Nrows ? g1 : Nrows - 1;
    int c2 = g2 < Nrows ? g2 : Nrows - 1;
    int c3 = g3 < Nrows ? g3 : Nrows - 1;
    xp0 = X + (size_t)(gidx ? gidx[c0] : c0) * H;
    xp1 = X + (size_t)(gidx ? gidx[c1] : c1) * H;
    xp2 = X + (size_t)(gidx ? gidx[c2] : c2) * H;
    xp3 = X + (size_t)(gidx ? gidx[c3] : c3) * H;
  }
  float a0[4] = {0,0,0,0}, a1[4] = {0,0,0,0}, a2[4] = {0,0,0,0}, a3[4] = {0,0,0,0};
  #pragma unroll 2
  for (int k = 0; k < H; k += 4) {
    float4 x0 = *(const float4*)(xp0 + k);
    float4 x1 = *(const float4*)(xp1 + k);
    float4 x2 = *(const float4*)(xp2 + k);
    float4 x3 = *(const float4*)(xp3 + k);
    float4 w0 = *(const float4*)&Ws[k + 0][cg4];
    float4 w1 = *(const float4*)&Ws[k + 1][cg4];
    float4 w2 = *(const float4*)&Ws[k + 2][cg4];
    float4 w3 = *(const float4*)&Ws[k + 3][cg4];
    FMA4(a0, x0.x, w0) FMA4(a0, x0.y, w1) FMA4(a0, x0.z, w2) FMA4(a0, x0.w, w3)
    FMA4(a1, x1.x, w0) FMA4(a1, x1.y, w1) FMA4(a1, x1.z, w2) FMA4(a1, x1.w, w3)
    FMA4(a2, x2.x, w0) FMA4(a2, x2.y, w1) FMA4(a2, x2.z, w2) FMA4(a2, x2.w, w3)
    FMA4(a3, x3.x, w0) FMA4(a3, x3.y, w1) FMA4(a3, x3.z, w2) FMA4(a3, x3.w, w3)
  }
  if (g0 < Nrows) *(float4*)(Y + (size_t)g0 * H + bn + cg4) = make_float4(a0[0], a0[1], a0[2], a0[3]);
  if (g1 < Nrows) *(float4*)(Y + (size_t)g1 * H + bn + cg4) = make_float4(a1[0], a1[1], a1[2], a1[3]);
  if (g2 < Nrows) *(float4*)(Y + (size_t)g2 * H + bn + cg4) = make_float4(a2[0], a2[1], a2[2], a2[3]);
  if (g3 < Nrows) *(float4*)(Y + (size_t)g3 * H + bn + cg4) = make_float4(a3[0], a3[1], a3[2], a3[3]);
}

// ---------------- Aggregation: out[v] = b + dinv[v]^2*xw[v] + sum_e norm_e * xw[src_e] ----------------

__global__ __launch_bounds__(256) void k_agg(const float* __restrict__ XW,
    const int2* __restrict__ elist, const int* __restrict__ offs, const int* __restrict__ cnt,
    const float* __restrict__ dinv, const float* __restrict__ bias,
    float* __restrict__ out, int n, int relu) {
  int wid = (blockIdx.x * 256 + threadIdx.x) >> 6;  // one wave per node
  int lane = threadIdx.x & 63;
  if (wid >= n) return;
  const float2* xw2 = (const float2*)XW;
  float di = dinv[wid];
  float2 s = xw2[(size_t)wid * 64 + lane];
  float ax = di * di * s.x, ay = di * di * s.y;   // self loop
  int beg = offs[wid], end = beg + cnt[wid];
  int e = beg;
  for (; e + 4 <= end; e += 4) {
    int2 e0 = elist[e], e1 = elist[e + 1], e2 = elist[e + 2], e3 = elist[e + 3];
    float2 v0 = xw2[(size_t)e0.x * 64 + lane];
    float2 v1 = xw2[(size_t)e1.x * 64 + lane];
    float2 v2 = xw2[(size_t)e2.x * 64 + lane];
    float2 v3 = xw2[(size_t)e3.x * 64 + lane];
    float n0 = __int_as_float(e0.y), n1 = __int_as_float(e1.y);
    float n2 = __int_as_float(e2.y), n3 = __int_as_float(e3.y);
    ax = fmaf(n0, v0.x, ax); ay = fmaf(n0, v0.y, ay);
    ax = fmaf(n1, v1.x, ax); ay = fmaf(n1, v1.y, ay);
    ax = fmaf(n2, v2.x, ax); ay = fmaf(n2, v2.y, ay);
    ax = fmaf(n3, v3.x, ax); ay = fmaf(n3, v3.y, ay);
  }
  for (; e < end; ++e) {
    int2 ee = elist[e];
    float2 vv = xw2[(size_t)ee.x * 64 + lane];
    float nn = __int_as_float(ee.y);
    ax = fmaf(nn, vv.x, ax); ay = fmaf(nn, vv.y, ay);
  }
  float2 bb = ((const float2*)bias)[lane];
  ax += bb.x; ay += bb.y;
  if (relu) { ax = fmaxf(ax, 0.f); ay = fmaxf(ay, 0.f); }
  ((float2*)out)[(size_t)wid * 64 + lane] = make_float2(ax, ay);
}

// ---------------- Head: centers, pair product, lin1+relu, lin2 ----------------

__global__ __launch_bounds__(128) void k_head(const float* __restrict__ X,
    const int* __restrict__ batch, int n,
    const float* __restrict__ W1, const float* __restrict__ b1,
    const float* __restrict__ W2, const float* __restrict__ b2,
    float* __restrict__ out, int G) {
  int g = blockIdx.x, t = threadIdx.x;
  int lo = 0, hi = n;                      // searchsorted(batch, g, side='left')
  while (lo < hi) { int mid = (lo + hi) >> 1; if (batch[mid] < g) lo = mid + 1; else hi = mid; }
  __shared__ float hs[H];
  hs[t] = X[(size_t)lo * H + t] * X[(size_t)(lo + 1) * H + t];
  __syncthreads();
  float a = b1[t];
  #pragma unroll 8
  for (int k = 0; k < H; ++k) a = fmaf(hs[k], W1[k * H + t], a);
  a = fmaxf(a, 0.f);
  a *= W2[t];
  for (int off = 32; off > 0; off >>= 1) a += __shfl_down(a, off);
  __shared__ float wsum[2];
  if ((t & 63) == 0) wsum[t >> 6] = a;
  __syncthreads();
  if (t == 0) out[g] = wsum[0] + wsum[1] + b2[0];
}

// ---------------- launch ----------------

extern "C" void kernel_launch(void* const* d_in, const int* in_sizes, int n_in,
                              void* d_out, int out_size, void* d_ws, size_t ws_size,
                              hipStream_t stream) {
  const int* z     = (const int*)d_in[0];
  const int* eidx  = (const int*)d_in[1];
  const int* batch = (const int*)d_in[2];
  const float* ew  = (const float*)d_in[3];
  const float* ztab= (const float*)d_in[4];
  const float *W0, *W1, *W2, *b0, *b1, *b2, *l1W, *l1b, *l2W, *l2b;
  if (n_in >= 15) {  // tuples flattened to separate inputs
    W0 = (const float*)d_in[5];  W1 = (const float*)d_in[6];  W2 = (const float*)d_in[7];
    b0 = (const float*)d_in[8];  b1 = (const float*)d_in[9];  b2 = (const float*)d_in[10];
    l1W = (const float*)d_in[11]; l1b = (const float*)d_in[12];
    l2W = (const float*)d_in[13]; l2b = (const float*)d_in[14];
  } else {           // tuples packed into one array each
    const float* Wss = (const float*)d_in[5];
    W0 = Wss; W1 = Wss + H * H; W2 = Wss + 2 * H * H;
    const float* bs = (const float*)d_in[6];
    b0 = bs; b1 = bs + H; b2 = bs + 2 * H;
    l1W = (const float*)d_in[7]; l1b = (const float*)d_in[8];
    l2W = (const float*)d_in[9]; l2b = (const float*)d_in[10];
  }
  int N = in_sizes[0];
  int E = in_sizes[3];
  int G = out_size;
  float* fout = (float*)d_out;

  size_t woff = 0;
  auto alloc = [&](size_t bytes) {
    void* p = (char*)d_ws + woff;
    woff += (bytes + 255) & ~(size_t)255;
    return p;
  };
  float* bufA  = (float*)alloc((size_t)N * H * 4);
  float* bufB  = (float*)alloc((size_t)N * H * 4);
  float* xw    = (float*)alloc((size_t)N * H * 4);
  float* dinv  = (float*)alloc((size_t)N * 4);
  int*   cnt   = (int*)alloc((size_t)N * 4);
  int*   offs  = (int*)alloc((size_t)N * 4);
  int*   cur   = (int*)alloc((size_t)N * 4);
  int*   bsums = (int*)alloc(4096);
  int2*  elist = (int2*)alloc((size_t)E * 8);

  const int* erow = eidx;
  const int* ecol = eidx + E;

  hipMemsetAsync(cnt, 0, (size_t)N * 4, stream);
  hipMemsetAsync(cur, 0, (size_t)N * 4, stream);

  int nb = (N + 255) / 256;
  int eb = (E + 255) / 256;
  k_init_dinv<<<nb, 256, 0, stream>>>(dinv, N);
  k_deg_count<<<eb, 256, 0, stream>>>(ecol, ew, dinv, cnt, E);
  k_dinv<<<nb, 256, 0, stream>>>(dinv, N);
  k_scan1<<<nb, 256, 0, stream>>>(cnt, offs, bsums, N);
  k_scan2<<<1, 512, 0, stream>>>(bsums, nb);
  k_scan3<<<nb, 256, 0, stream>>>(offs, bsums, N);
  k_fill<<<eb, 256, 0, stream>>>(erow, ecol, ew, dinv, offs, cur, elist, E);

  dim3 ggrid((N + GBM - 1) / GBM, H / GBN);
  int agrid = (N + 3) / 4;  // 4 waves (nodes) per 256-thread block

  // layer 0 (embedding fused into GEMM via gidx = z)
  k_gemm<<<ggrid, 256, 0, stream>>>(ztab, z, W0, xw, N);
  k_agg<<<agrid, 256, 0, stream>>>(xw, elist, offs, cnt, dinv, b0, bufA, N, 1);
  // layer 1
  k_gemm<<<ggrid, 256, 0, stream>>>(bufA, nullptr, W1, xw, N);
  k_agg<<<agrid, 256, 0, stream>>>(xw, elist, offs, cnt, dinv, b1, bufB, N, 1);
  // layer 2
  k_gemm<<<ggrid, 256, 0, stream>>>(bufB, nullptr, W2, xw, N);
  k_agg<<<agrid, 256, 0, stream>>>(xw, elist, offs, cnt, dinv, b2, bufA, N, 0);

  k_head<<<G, 128, 0, stream>>>(bufA, batch, N, l1W, l1b, l2W, l2b, fout, G);
}

// Round 2
// 697.858 us; speedup vs baseline: 1.1146x; 1.1146x over previous
//
#include <hip/hip_runtime.h>
#include <hip/hip_bf16.h>

#define H 128
#define GBM 64
#define GBN 64
#define CNT_SCALE 16777216.0   // 2^24: deg-double encodes cnt*2^24 + sum_w

// ---------------- norm / CSR build ----------------

// one fused atomic per edge: deg[col] += w + 2^24  (count in high part)
__global__ void k_deg(const int* __restrict__ col, const float* __restrict__ w,
                      double* __restrict__ deg, int E) {
  int e = blockIdx.x * 256 + threadIdx.x;
  if (e >= E) return;
  atomicAdd(&deg[col[e]], (double)w[e] + CNT_SCALE);
}

__global__ void k_dinv(const double* __restrict__ dsum, float* __restrict__ dinv,
                       int* __restrict__ cnt, int n) {
  int i = blockIdx.x * 256 + threadIdx.x;
  if (i >= n) return;
  double v = dsum[i];
  double c = floor(v * (1.0 / CNT_SCALE));
  double s = v - c * CNT_SCALE + 1.0;          // + self-loop weight
  dinv[i] = (float)(1.0 / sqrt(s));
  cnt[i] = (int)c;
}

__global__ void k_scan1(const int* __restrict__ cnt, int* __restrict__ offs,
                        int* __restrict__ bsums, int n) {
  __shared__ int s[256];
  int t = threadIdx.x, i = blockIdx.x * 256 + t;
  int v = (i < n) ? cnt[i] : 0;
  s[t] = v; __syncthreads();
  for (int off = 1; off < 256; off <<= 1) {
    int x = 0;
    if (t >= off) x = s[t - off];
    __syncthreads();
    if (t >= off) s[t] += x;
    __syncthreads();
  }
  if (i < n) offs[i] = s[t] - v;          // exclusive scan within block
  if (t == 255) bsums[blockIdx.x] = s[t]; // block total
}

__global__ void k_scan2(int* __restrict__ bsums, int nb) {
  __shared__ int s[512];
  int t = threadIdx.x;
  int v = (t < nb) ? bsums[t] : 0;
  s[t] = v; __syncthreads();
  for (int off = 1; off < 512; off <<= 1) {
    int x = 0;
    if (t >= off) x = s[t - off];
    __syncthreads();
    if (t >= off) s[t] += x;
    __syncthreads();
  }
  if (t < nb) bsums[t] = s[t] - v;        // exclusive scan of block sums
}

// offs += block base; cur = offs (atomic cursors start at segment base)
__global__ void k_scan3(int* __restrict__ offs, int* __restrict__ cur,
                        const int* __restrict__ bsums, int n) {
  int i = blockIdx.x * 256 + threadIdx.x;
  if (i < n) { int o = offs[i] + bsums[blockIdx.x]; offs[i] = o; cur[i] = o; }
}

// after this kernel cur[v] == offs[v] + cnt[v] == segment end
__global__ void k_fill(const int* __restrict__ row, const int* __restrict__ col,
                       const float* __restrict__ ew, const float* __restrict__ dinv,
                       int* __restrict__ cur, int2* __restrict__ elist, int E) {
  int e = blockIdx.x * 256 + threadIdx.x;
  if (e >= E) return;
  int c = col[e], r = row[e];
  int pos = atomicAdd(&cur[c], 1);
  elist[pos] = make_int2(r, __float_as_int(dinv[r] * ew[e] * dinv[c]));
}

// ---------------- GEMM: Y[r] = X[gidx? gidx[r] : r] @ W  (fp32, 64x64 tile) ----------------

#define FMA4(A, xs, wv) { A[0] = fmaf(xs, wv.x, A[0]); A[1] = fmaf(xs, wv.y, A[1]); \
                          A[2] = fmaf(xs, wv.z, A[2]); A[3] = fmaf(xs, wv.w, A[3]); }

__global__ __launch_bounds__(256, 2) void k_gemm(const float* __restrict__ X,
    const int* __restrict__ gidx, const float* __restrict__ Wg,
    float* __restrict__ Y, int Nrows) {
  __shared__ float Ws[H][GBN + 4];
  int tid = threadIdx.x;
  int bm = blockIdx.x * GBM;
  int bn = blockIdx.y * GBN;
  for (int i = tid; i < H * (GBN / 4); i += 256) {
    int k = i >> 4, c4 = (i & 15) * 4;
    *(float4*)&Ws[k][c4] = *(const float4*)(Wg + k * H + bn + c4);
  }
  __syncthreads();
  int rg = tid >> 4, cg = tid & 15;
  int cg4 = cg * 4;
  const float* xp0; const float* xp1; const float* xp2; const float* xp3;
  int g0 = bm + rg * 4 + 0, g1 = g0 + 1, g2 = g0 + 2, g3 = g0 + 3;
  {
    int c0 = g0 < Nrows ? g0 : Nrows - 1;
    int c1 = g1 < Nrows ? g1 : Nrows - 1;
    int c2 = g2 < Nrows ? g2 : Nrows - 1;
    int c3 = g3 < Nrows ? g3 : Nrows - 1;
    xp0 = X + (size_t)(gidx ? gidx[c0] : c0) * H;
    xp1 = X + (size_t)(gidx ? gidx[c1] : c1) * H;
    xp2 = X + (size_t)(gidx ? gidx[c2] : c2) * H;
    xp3 = X + (size_t)(gidx ? gidx[c3] : c3) * H;
  }
  float a0[4] = {0,0,0,0}, a1[4] = {0,0,0,0}, a2[4] = {0,0,0,0}, a3[4] = {0,0,0,0};
  #pragma unroll 2
  for (int k = 0; k < H; k += 4) {
    float4 x0 = *(const float4*)(xp0 + k);
    float4 x1 = *(const float4*)(xp1 + k);
    float4 x2 = *(const float4*)(xp2 + k);
    float4 x3 = *(const float4*)(xp3 + k);
    float4 w0 = *(const float4*)&Ws[k + 0][cg4];
    float4 w1 = *(const float4*)&Ws[k + 1][cg4];
    float4 w2 = *(const float4*)&Ws[k + 2][cg4];
    float4 w3 = *(const float4*)&Ws[k + 3][cg4];
    FMA4(a0, x0.x, w0) FMA4(a0, x0.y, w1) FMA4(a0, x0.z, w2) FMA4(a0, x0.w, w3)
    FMA4(a1, x1.x, w0) FMA4(a1, x1.y, w1) FMA4(a1, x1.z, w2) FMA4(a1, x1.w, w3)
    FMA4(a2, x2.x, w0) FMA4(a2, x2.y, w1) FMA4(a2, x2.z, w2) FMA4(a2, x2.w, w3)
    FMA4(a3, x3.x, w0) FMA4(a3, x3.y, w1) FMA4(a3, x3.z, w2) FMA4(a3, x3.w, w3)
  }
  if (g0 < Nrows) *(float4*)(Y + (size_t)g0 * H + bn + cg4) = make_float4(a0[0], a0[1], a0[2], a0[3]);
  if (g1 < Nrows) *(float4*)(Y + (size_t)g1 * H + bn + cg4) = make_float4(a1[0], a1[1], a1[2], a1[3]);
  if (g2 < Nrows) *(float4*)(Y + (size_t)g2 * H + bn + cg4) = make_float4(a2[0], a2[1], a2[2], a2[3]);
  if (g3 < Nrows) *(float4*)(Y + (size_t)g3 * H + bn + cg4) = make_float4(a3[0], a3[1], a3[2], a3[3]);
}

// ---------------- Aggregation ----------------
// one wave per node; two 32-lane halves each gather full 512B rows as float4,
// processing edges beg+half, beg+half+2, ... ; halves combined via shfl_xor(32).

#define EFMA(nn, vv) { acc.x = fmaf(nn, vv.x, acc.x); acc.y = fmaf(nn, vv.y, acc.y); \
                       acc.z = fmaf(nn, vv.z, acc.z); acc.w = fmaf(nn, vv.w, acc.w); }

__global__ __launch_bounds__(256) void k_agg(const float* __restrict__ XW,
    const int2* __restrict__ elist, const int* __restrict__ offs, const int* __restrict__ endp,
    const float* __restrict__ dinv, const float* __restrict__ bias,
    float* __restrict__ out, int n, int relu) {
  int wid = (blockIdx.x * 256 + threadIdx.x) >> 6;
  if (wid >= n) return;
  int lane = threadIdx.x & 63;
  int half = lane >> 5;
  int c4 = lane & 31;
  const float4* xw4 = (const float4*)XW;
  int beg = offs[wid], end = endp[wid];
  float4 acc;
  if (half == 0) {
    float di = dinv[wid];
    float d2 = di * di;
    float4 s = xw4[(size_t)wid * 32 + c4];
    acc = make_float4(d2 * s.x, d2 * s.y, d2 * s.z, d2 * s.w);
  } else {
    acc = make_float4(0.f, 0.f, 0.f, 0.f);
  }
  int e = beg + half;
  for (; e + 6 < end; e += 8) {     // 4 edges per half in flight
    int2 e0 = elist[e], e1 = elist[e + 2], e2 = elist[e + 4], e3 = elist[e + 6];
    float4 v0 = xw4[(size_t)e0.x * 32 + c4];
    float4 v1 = xw4[(size_t)e1.x * 32 + c4];
    float4 v2 = xw4[(size_t)e2.x * 32 + c4];
    float4 v3 = xw4[(size_t)e3.x * 32 + c4];
    float n0 = __int_as_float(e0.y), n1 = __int_as_float(e1.y);
    float n2 = __int_as_float(e2.y), n3 = __int_as_float(e3.y);
    EFMA(n0, v0) EFMA(n1, v1) EFMA(n2, v2) EFMA(n3, v3)
  }
  for (; e < end; e += 2) {
    int2 ee = elist[e];
    float4 vv = xw4[(size_t)ee.x * 32 + c4];
    float nn = __int_as_float(ee.y);
    EFMA(nn, vv)
  }
  acc.x += __shfl_xor(acc.x, 32);
  acc.y += __shfl_xor(acc.y, 32);
  acc.z += __shfl_xor(acc.z, 32);
  acc.w += __shfl_xor(acc.w, 32);
  if (half == 0) {
    float4 bb = ((const float4*)bias)[c4];
    acc.x += bb.x; acc.y += bb.y; acc.z += bb.z; acc.w += bb.w;
    if (relu) {
      acc.x = fmaxf(acc.x, 0.f); acc.y = fmaxf(acc.y, 0.f);
      acc.z = fmaxf(acc.z, 0.f); acc.w = fmaxf(acc.w, 0.f);
    }
    ((float4*)out)[(size_t)wid * 32 + c4] = acc;
  }
}

// ---------------- Head ----------------

__global__ __launch_bounds__(128) void k_head(const float* __restrict__ X,
    const int* __restrict__ batch, int n,
    const float* __restrict__ W1, const float* __restrict__ b1,
    const float* __restrict__ W2, const float* __restrict__ b2,
    float* __restrict__ out, int G) {
  int g = blockIdx.x, t = threadIdx.x;
  int lo = 0, hi = n;
  while (lo < hi) { int mid = (lo + hi) >> 1; if (batch[mid] < g) lo = mid + 1; else hi = mid; }
  __shared__ float hs[H];
  hs[t] = X[(size_t)lo * H + t] * X[(size_t)(lo + 1) * H + t];
  __syncthreads();
  float a = b1[t];
  #pragma unroll 8
  for (int k = 0; k < H; ++k) a = fmaf(hs[k], W1[k * H + t], a);
  a = fmaxf(a, 0.f);
  a *= W2[t];
  for (int off = 32; off > 0; off >>= 1) a += __shfl_down(a, off);
  __shared__ float wsum[2];
  if ((t & 63) == 0) wsum[t >> 6] = a;
  __syncthreads();
  if (t == 0) out[g] = wsum[0] + wsum[1] + b2[0];
}

// ---------------- launch ----------------

extern "C" void kernel_launch(void* const* d_in, const int* in_sizes, int n_in,
                              void* d_out, int out_size, void* d_ws, size_t ws_size,
                              hipStream_t stream) {
  const int* z     = (const int*)d_in[0];
  const int* eidx  = (const int*)d_in[1];
  const int* batch = (const int*)d_in[2];
  const float* ew  = (const float*)d_in[3];
  const float* ztab= (const float*)d_in[4];
  const float *W0, *W1, *W2, *b0, *b1, *b2, *l1W, *l1b, *l2W, *l2b;
  if (n_in >= 15) {
    W0 = (const float*)d_in[5];  W1 = (const float*)d_in[6];  W2 = (const float*)d_in[7];
    b0 = (const float*)d_in[8];  b1 = (const float*)d_in[9];  b2 = (const float*)d_in[10];
    l1W = (const float*)d_in[11]; l1b = (const float*)d_in[12];
    l2W = (const float*)d_in[13]; l2b = (const float*)d_in[14];
  } else {
    const float* Wss = (const float*)d_in[5];
    W0 = Wss; W1 = Wss + H * H; W2 = Wss + 2 * H * H;
    const float* bs = (const float*)d_in[6];
    b0 = bs; b1 = bs + H; b2 = bs + 2 * H;
    l1W = (const float*)d_in[7]; l1b = (const float*)d_in[8];
    l2W = (const float*)d_in[9]; l2b = (const float*)d_in[10];
  }
  int N = in_sizes[0];
  int E = in_sizes[3];
  int G = out_size;
  float* fout = (float*)d_out;

  size_t woff = 0;
  auto alloc = [&](size_t bytes) {
    void* p = (char*)d_ws + woff;
    woff += (bytes + 255) & ~(size_t)255;
    return p;
  };
  float*  bufA  = (float*)alloc((size_t)N * H * 4);
  float*  bufB  = (float*)alloc((size_t)N * H * 4);
  float*  xw    = (float*)alloc((size_t)N * H * 4);
  double* dsum  = (double*)alloc((size_t)N * 8);
  float*  dinv  = (float*)alloc((size_t)N * 4);
  int*    cnt   = (int*)alloc((size_t)N * 4);
  int*    offs  = (int*)alloc((size_t)N * 4);
  int*    cur   = (int*)alloc((size_t)N * 4);
  int*    bsums = (int*)alloc(4096);
  int2*   elist = (int2*)alloc((size_t)E * 8);

  const int* erow = eidx;
  const int* ecol = eidx + E;

  hipMemsetAsync(dsum, 0, (size_t)N * 8, stream);

  int nb = (N + 255) / 256;
  int eb = (E + 255) / 256;
  k_deg<<<eb, 256, 0, stream>>>(ecol, ew, dsum, E);
  k_dinv<<<nb, 256, 0, stream>>>(dsum, dinv, cnt, N);
  k_scan1<<<nb, 256, 0, stream>>>(cnt, offs, bsums, N);
  k_scan2<<<1, 512, 0, stream>>>(bsums, nb);
  k_scan3<<<nb, 256, 0, stream>>>(offs, cur, bsums, N);
  k_fill<<<eb, 256, 0, stream>>>(erow, ecol, ew, dinv, cur, elist, E);
  // cur[v] is now segment end

  dim3 ggrid((N + GBM - 1) / GBM, H / GBN);
  int agrid = (N + 3) / 4;

  // layer 0 (embedding fused into GEMM via gidx = z)
  k_gemm<<<ggrid, 256, 0, stream>>>(ztab, z, W0, xw, N);
  k_agg<<<agrid, 256, 0, stream>>>(xw, elist, offs, cur, dinv, b0, bufA, N, 1);
  // layer 1
  k_gemm<<<ggrid, 256, 0, stream>>>(bufA, nullptr, W1, xw, N);
  k_agg<<<agrid, 256, 0, stream>>>(xw, elist, offs, cur, dinv, b1, bufB, N, 1);
  // layer 2
  k_gemm<<<ggrid, 256, 0, stream>>>(bufB, nullptr, W2, xw, N);
  k_agg<<<agrid, 256, 0, stream>>>(xw, elist, offs, cur, dinv, b2, bufA, N, 0);

  k_head<<<G, 128, 0, stream>>>(bufA, batch, N, l1W, l1b, l2W, l2b, fout, G);
}